// Round 14
// baseline (77.364 us; speedup 1.0000x reference)
//
#include <hip/hip_runtime.h>
#include <utility>

// reference == inverse(M M^T + EPS*I) per pixel, M = x[b,:,:,h,w]^T (16x64)
// x: [B=4, C=64, K=16, H=128, W=128] f32 ; out: [B,H,W,16,16] f32
// Fused, 256 px/block, 256 blocks, 512 threads (8 waves):
//   wave wv -> (G = wv&1: pair group, ph = wv>>1: pixel quarter), px = ph*64+lane
//   phase 1: gram via global_load_lds dbuf; chunk = 1c x 16k x 256px = 16 KB.
//            256 contiguous px span two h-rows -> each staging instruction is
//            ONE 1 KB contiguous DRAM burst (2x round-13's 512 B).
//   phase 2: acc[68] -> tri[136][259] (+EPS diag), disjoint (rows G, cols ph)
//   phase 3: G==0 waves (ph 0..3): tri -> REGISTER Cholesky -> L^-1 -> M^T M -> tri
//   phase 4: 512 threads: element e = tid&255, a-half = tid>>8, coalesced stores
// LDS: union{stage 2x16KB, tri 137.6KB} = 137.6KB -> 1 block/CU, 2 waves/SIMD
// (same waves/SIMD as round 13); __launch_bounds__(512,2) caps VGPR at 256.

#define EPSR 1e-6f
#define TS3 259                    // tri row stride; 259 mod 32 = 3 (bank spread)

__device__ __host__ constexpr int rowof(int t) {
    int i = 0;
    while ((i + 1) * (i + 2) / 2 <= t) ++i;
    return i;
}
__device__ __host__ constexpr int colof(int t) { return t - rowof(t) * (rowof(t) + 1) / 2; }

__device__ __forceinline__ constexpr int tidx(int i, int j) {  // i >= j
    return i * (i + 1) / 2 + j;
}

#define GLOAD_LDS16(gp, lp)                                                       \
    __builtin_amdgcn_global_load_lds(                                             \
        (const __attribute__((address_space(1))) void*)(gp),                      \
        (__attribute__((address_space(3))) void*)(lp), 16, 0, 0)

// ---------------- pair-split template machinery (68/group) ----------------

template<int P>
__device__ __forceinline__ void fma_pair(const float (&m)[16], float& a) {
    a = fmaf(m[rowof(P)], m[colof(P)], a);
}

template<int G, int... TT>
__device__ __forceinline__ void fma_group(const float (&m)[16], float (&acc)[68],
                                          std::integer_sequence<int, TT...>) {
    (fma_pair<G * 68 + TT>(m, acc[TT]), ...);
}

template<int G>
__device__ __forceinline__ void chunk_fma1(const float* __restrict__ buf, int px,
                                           float (&acc)[68]) {
    float m[16];
    #pragma unroll
    for (int k = 0; k < 16; ++k) m[k] = buf[k * 256 + px];
    fma_group<G>(m, acc, std::make_integer_sequence<int, 68>{});
}

template<int P>
__device__ __forceinline__ void store_tri_pair(float* __restrict__ tri, int px, float v) {
    constexpr bool diag = (rowof(P) == colof(P));
    tri[P * TS3 + px] = diag ? (v + EPSR) : v;
}

template<int G, int... TT>
__device__ __forceinline__ void store_tri_group(float* __restrict__ tri, int px,
                                                const float (&acc)[68],
                                                std::integer_sequence<int, TT...>) {
    (store_tri_pair<G * 68 + TT>(tri, px, acc[TT]), ...);
}

// ---------------- fused kernel ----------------

union SMem {
    float stage[2][4096];      // 2 x 16 KB: [k*256 + px]
    float tri[136 * TS3];      // 137.6 KB; row = pair index, col = pixel
};

__global__ __launch_bounds__(512, 2)
void fused_gram_inv(const float* __restrict__ x, float* __restrict__ out) {
    __shared__ __align__(16) SMem sm;

    const int tid = threadIdx.x;
    const int lane = tid & 63;
    const int wv = tid >> 6;                  // 0..7
    const int G = wv & 1;                     // pair group (0: pairs 0-67, 1: 68-135)
    const int ph = wv >> 1;                   // pixel quarter (0..3)
    const int px = ph * 64 + lane;            // this thread's pixel
    const int p0 = blockIdx.x * 256;
    const int b = blockIdx.x >> 6;            // 64 blocks per batch
    const int hw0 = p0 & 16383;

    // staging src: lane l covers px 4l..4l+3 of one k-row (16 B/lane ->
    // one wave-instr = 1 KB CONTIGUOUS global read, lane-linear in LDS)
    const float* gbase = x + (size_t)b * 16777216 + hw0 + (size_t)lane * 4;

    float acc[68];
    #pragma unroll
    for (int t = 0; t < 68; ++t) acc[t] = 0.0f;

    // chunk c: 16 k-rows; wave wv stages k = 2wv, 2wv+1 (2 instrs x 1 KB)
    auto STAGE = [&](int bufi, int c) {
        const float* gp = gbase + (size_t)c * 262144;
        #pragma unroll
        for (int q = 0; q < 2; ++q) {
            const int k = wv * 2 + q;
            GLOAD_LDS16(gp + (size_t)k * 16384, &sm.stage[bufi][k * 256]);
        }
    };

    // ---- phase 1: gram, dbuf pipeline (64 chunks of 1 c) ----
    STAGE(0, 0);
    for (int t = 0; t < 64; ++t) {
        __syncthreads();                              // vmcnt(0) drain + barrier
        if (t < 63) STAGE((t + 1) & 1, t + 1);        // prefetch next chunk
        const float* buf = sm.stage[t & 1];
        if (G == 0) chunk_fma1<0>(buf, px, acc);
        else        chunk_fma1<1>(buf, px, acc);
    }
    __syncthreads();   // all stage reads done before aliasing stage as tri

    // ---- phase 2: acc -> tri (+EPS on diag); disjoint (rows G, cols ph) ----
    if (G == 0) store_tri_group<0>(sm.tri, px, acc, std::make_integer_sequence<int, 68>{});
    else        store_tri_group<1>(sm.tri, px, acc, std::make_integer_sequence<int, 68>{});
    __syncthreads();

    // ---- phase 3: G==0 waves, lane = own px, REGISTER inversion ----
    if (G == 0) {
        float s[136];
        #pragma unroll
        for (int t = 0; t < 136; ++t) s[t] = sm.tri[t * TS3 + px];

        // Cholesky in place: off-diag = L[i][j], diag = 1/L[j][j]
        #pragma unroll
        for (int j = 0; j < 16; ++j) {
            float d = s[tidx(j, j)];
            #pragma unroll
            for (int q = 0; q < j; ++q) d = fmaf(-s[tidx(j, q)], s[tidx(j, q)], d);
            const float invd = 1.0f / sqrtf(d);
            s[tidx(j, j)] = invd;
            #pragma unroll
            for (int i = j + 1; i < 16; ++i) {
                float v = s[tidx(i, j)];
                #pragma unroll
                for (int q = 0; q < j; ++q) v = fmaf(-s[tidx(i, q)], s[tidx(j, q)], v);
                s[tidx(i, j)] = v * invd;
            }
        }

        // M = L^{-1} in place (diag already inverted)
        #pragma unroll
        for (int j = 0; j < 16; ++j) {
            #pragma unroll
            for (int i = j + 1; i < 16; ++i) {
                float sum = s[tidx(i, j)] * s[tidx(j, j)];
                #pragma unroll
                for (int q = j + 1; q < i; ++q)
                    sum = fmaf(s[tidx(i, q)], s[tidx(q, j)], sum);
                s[tidx(i, j)] = -s[tidx(i, i)] * sum;
            }
        }

        // A^{-1} = M^T M in place
        #pragma unroll
        for (int j = 0; j < 16; ++j) {
            #pragma unroll
            for (int i = j; i < 16; ++i) {
                float sum = 0.0f;
                #pragma unroll
                for (int q = i; q < 16; ++q)
                    sum = fmaf(s[tidx(q, i)], s[tidx(q, j)], sum);
                s[tidx(i, j)] = sum;
            }
        }

        // writeback
        #pragma unroll
        for (int t = 0; t < 136; ++t) sm.tri[t * TS3 + px] = s[t];
    }
    __syncthreads();

    // ---- phase 4: gather-store, thread = element (tid&255), a-half (tid>>8) ----
    const int e = tid & 255;            // 0..255 -> (i,j)
    const int half = tid >> 8;          // 0 or 1
    const int i = e >> 4, j = e & 15;
    const int hi = i > j ? i : j;
    const int lo = i + j - hi;
    const int trow = hi * (hi + 1) / 2 + lo;
    float* gout = out + (size_t)p0 * 256;
    #pragma unroll 8
    for (int a = half * 128; a < half * 128 + 128; ++a) {
        gout[(size_t)a * 256 + e] = sm.tri[trow * TS3 + a];
    }
}

extern "C" void kernel_launch(void* const* d_in, const int* in_sizes, int n_in,
                              void* d_out, int out_size, void* d_ws, size_t ws_size,
                              hipStream_t stream) {
    const float* x = (const float*)d_in[0];
    float* out = (float*)d_out;
    hipLaunchKernelGGL(fused_gram_inv, dim3(256), dim3(512), 0, stream, x, out);
}